// Round 2
// baseline (260.992 us; speedup 1.0000x reference)
//
#include <hip/hip_runtime.h>

// Problem constants
#define BB 128
#define TT 6
#define KK 64
#define DD 8
#define HH 128
#define NSTEP 5
#define LDP 136      // padded LDS row (u16 elems): 272B = 17*16B, 16B-aligned rows
#define PREDSZ (BB*NSTEP*KK*DD)   // 327680

typedef unsigned short u16;
typedef unsigned int   u32;
typedef _Float16 f16;
typedef __attribute__((ext_vector_type(8))) _Float16 f16x8;
typedef __attribute__((ext_vector_type(4))) float f32x4;
typedef __attribute__((ext_vector_type(2))) unsigned int u32x2;
typedef __attribute__((ext_vector_type(2))) _Float16 h2;

union h2u { u32 u; h2 h; };
union hu  { u16 u; f16 h; };

__device__ __forceinline__ u16 f2h_bits(float f){
  hu v; v.h = (f16)f; return v.u;     // v_cvt_f16_f32, 1 instr
}

// ---------------- ws layout (u16 element offsets) ----------------
// All K=128 matrices stored as wave-coalesced f16 fragments:
//   FR[g=8][kc=4][lane=64][8] : elem off = g*2048 + kc*512 + lane*8
// so one frag load = 64 lanes x 16B contiguous (1KB, perfectly coalesced).
// UW1 (K=256): FR[g=8][kc=8][lane=64][8] : off = g*4096 + kc*512 + lane*8.
#define O_WIA  0
#define O_WIB  16384
#define O_SW1  32768
#define O_SW2  49152
#define O_IW2  65536
#define O_UW2  81920
#define O_DW1  98304
#define O_EW2  114688
#define O_DET  131072
#define O_UW1  147456   // 32768 elems
#define O_DW2T 180224   // dw2 transposed f16 [8][128]
#define O_DEB  181248   // 128 f32 (de bias), float index 90624

// ---- GEMM: O(64x128) = A(64x128)@W [*ascale + bias] ----
// 16 waves: wave w -> col group wn=w&7 (n = wn*16 + l15), m-half wm=w>>3 (2 m-tiles).
// W frags JIT-loaded from ws (wave-coalesced, L1/L2-hot; waves wn and wn+8 share addrs).
template<bool RELU>
__device__ __forceinline__ void gemmJ(const u16 (*A)[LDP], const u16* __restrict__ wt,
    float ascale, float bias, u16 (*O)[LDP], int wn, int wm, int l15, int q, int n, int lane)
{
  f16x8 bf[4];
#pragma unroll
  for (int kc=0; kc<4; ++kc)
    bf[kc] = *(const f16x8*)(wt + (wn<<11) + (kc<<9) + (lane<<3));
#pragma unroll
  for (int mt=0; mt<2; ++mt){
    f32x4 acc = {0.f,0.f,0.f,0.f};
#pragma unroll
    for (int kc=0; kc<4; ++kc){
      f16x8 af = *(const f16x8*)&A[(wm<<5)+(mt<<4)+l15][(kc<<5)+(q<<3)];
      acc = __builtin_amdgcn_mfma_f32_16x16x32_f16(af, bf[kc], acc, 0,0,0);
    }
#pragma unroll
    for (int e=0; e<4; ++e){
      float v = acc[e]*ascale + bias;
      if (RELU) v = fmaxf(v, 0.f);
      O[(wm<<5)+(mt<<4)+(q<<2)+e][n] = f2h_bits(v);   // C/D: col=lane&15, row=q*4+e
    }
  }
}

// K=256 (update MLP layer1): A = [A1 | A2], relu out, uw1 frags JIT
__device__ __forceinline__ void gemm256J(const u16 (*A1)[LDP], const u16 (*A2)[LDP],
    const u16* __restrict__ wt, float bias, u16 (*O)[LDP], int wn, int wm, int l15, int q, int n, int lane)
{
  f16x8 bf[8];
#pragma unroll
  for (int kc=0; kc<8; ++kc)
    bf[kc] = *(const f16x8*)(wt + (wn<<12) + (kc<<9) + (lane<<3));
#pragma unroll
  for (int mt=0; mt<2; ++mt){
    f32x4 acc = {0.f,0.f,0.f,0.f};
#pragma unroll
    for (int kc=0; kc<8; ++kc){
      const u16 (*As)[LDP] = (kc<4) ? A1 : A2;
      f16x8 af = *(const f16x8*)&As[(wm<<5)+(mt<<4)+l15][((kc&3)<<5)+(q<<3)];
      acc = __builtin_amdgcn_mfma_f32_16x16x32_f16(af, bf[kc], acc, 0,0,0);
    }
#pragma unroll
    for (int e=0; e<4; ++e){
      float v = fmaxf(acc[e] + bias, 0.f);
      O[(wm<<5)+(mt<<4)+(q<<2)+e][n] = f2h_bits(v);
    }
  }
}

// Fused stage1: one pass over A-frags of P feeds 3 GEMMs:
//   Q = P@wia (f16), R = P@wib + ib1 (f16), S = relu(P@sw1 + sb1) (f16)
// wia/wib persistent in regs (32 VGPR); sw1 JIT.
__device__ __forceinline__ void stage1(const u16 (*P)[LDP],
    const f16x8* fa, const f16x8* fb, const u16* __restrict__ sw1w,
    float ib1v, float sb1v,
    u16 (*Q)[LDP], u16 (*R)[LDP], u16 (*S)[LDP],
    int wn, int wm, int l15, int q, int n, int lane)
{
  f16x8 fs[4];
#pragma unroll
  for (int kc=0; kc<4; ++kc)
    fs[kc] = *(const f16x8*)(sw1w + (wn<<11) + (kc<<9) + (lane<<3));
#pragma unroll
  for (int mt=0; mt<2; ++mt){
    f32x4 aA = {0.f,0.f,0.f,0.f}, aB = {0.f,0.f,0.f,0.f}, aS = {0.f,0.f,0.f,0.f};
#pragma unroll
    for (int kc=0; kc<4; ++kc){
      f16x8 af = *(const f16x8*)&P[(wm<<5)+(mt<<4)+l15][(kc<<5)+(q<<3)];
      aA = __builtin_amdgcn_mfma_f32_16x16x32_f16(af, fa[kc], aA, 0,0,0);
      aB = __builtin_amdgcn_mfma_f32_16x16x32_f16(af, fb[kc], aB, 0,0,0);
      aS = __builtin_amdgcn_mfma_f32_16x16x32_f16(af, fs[kc], aS, 0,0,0);
    }
#pragma unroll
    for (int e=0; e<4; ++e){
      const int row = (wm<<5)+(mt<<4)+(q<<2)+e;
      Q[row][n] = f2h_bits(aA[e]);
      R[row][n] = f2h_bits(aB[e]+ib1v);
      S[row][n] = f2h_bits(fmaxf(aS[e]+sb1v, 0.f));
    }
  }
}

// Qa := Ssum where Ssum[j,h] = sum_i relu(a[i,h]+b[j,h]); all f16.
// lanes=j; wave (wn,wm) owns 8 cols [wn*16+wm*8, +8): in-place, wave-disjoint.
__device__ __forceinline__ void interaction(u16 (*Qa)[LDP], const u16 (*Rb)[LDP], int wn, int wm, int lane)
{
  h2 z; z.x = (f16)0.f; z.y = (f16)0.f;
#pragma unroll
  for (int p=0; p<2; ++p){
    const int h = (wn<<4) + (wm<<3) + (p<<2);
    u32x2 bv = *(const u32x2*)&Rb[lane][h];
    h2u cb0, cb1; cb0.u = bv.x; cb1.u = bv.y;
    h2 s01 = z, s23 = z, t01 = z, t23 = z;
#pragma unroll 8
    for (int i=0; i<KK; i+=2){
      u32x2 a0 = *(const u32x2*)&Qa[i][h];      // lane-uniform broadcast
      u32x2 a1 = *(const u32x2*)&Qa[i+1][h];
      h2u x0, x1, y0, y1; x0.u = a0.x; x1.u = a0.y; y0.u = a1.x; y1.u = a1.y;
      s01 += __builtin_elementwise_max(x0.h + cb0.h, z);
      s23 += __builtin_elementwise_max(x1.h + cb1.h, z);
      t01 += __builtin_elementwise_max(y0.h + cb0.h, z);
      t23 += __builtin_elementwise_max(y1.h + cb1.h, z);
    }
    s01 += t01; s23 += t23;
    h2u o0, o1; o0.h = s01; o1.h = s23;       // store f16 directly (no f32 round-trip)
    u32x2 ov; ov.x = o0.u; ov.y = o1.u;
    *(u32x2*)&Qa[lane][h] = ov;
  }
}

// pred(64x8) = S(64x128,f16) @ dw2 + db2 -> global out only (side branch, tid<512)
__device__ __forceinline__ void dec_out(const u16 (*S)[LDP], const u16* __restrict__ dwt,
    float db2v, float* __restrict__ out, int b, int t, int tid)
{
  const int r = tid>>3, d = tid&7;
  float acc = db2v;
#pragma unroll
  for (int c=0; c<16; ++c){
    f16x8 hv = *(const f16x8*)&S[r][c<<3];
    f16x8 wv = *(const f16x8*)(dwt + (d<<7) + (c<<3));
#pragma unroll
    for (int j=0; j<8; ++j)
      acc += (float)hv[j] * (float)wv[j];
  }
  out[(size_t)(b*NSTEP + t)*(KK*DD) + (r<<3) + d] = acc;
}

// enc layer1 (K=8) from fp32 pred buffer — used once at start (1024 threads: 8 rows each)
__device__ __forceinline__ void mlp_in8(const float* pred, const float* __restrict__ W,
    const float* __restrict__ bias, u16 (*O)[LDP], int tid)
{
  const int h = tid & 127, rg = tid >> 7;    // rg in [0,8)
  float wv[DD];
#pragma unroll
  for (int d=0; d<DD; ++d) wv[d] = W[d*HH + h];
  const float bv = bias[h];
  for (int rr=0; rr<8; ++rr){
    const int r = (rg<<3) + rr;
    float v = bv;
#pragma unroll
    for (int d=0; d<DD; ++d) v += pred[r*DD + d] * wv[d];
    O[r][h] = f2h_bits(fmaxf(v, 0.f));
  }
}

// ---------------- prep: stage wave-coalesced f16 weight frags + fused DE matrix ----------------
__global__ void prep_kernel(
    const float* __restrict__ ew1, const float* __restrict__ eb1,
    const float* __restrict__ ew2, const float* __restrict__ sw1, const float* __restrict__ sw2,
    const float* __restrict__ iw1, const float* __restrict__ iw2, const float* __restrict__ uw1,
    const float* __restrict__ uw2, const float* __restrict__ dw1, const float* __restrict__ dw2,
    const float* __restrict__ db2, u16* __restrict__ ws)
{
  const int idx = blockIdx.x * 256 + threadIdx.x;
  if (idx < 147456){
    // nine K=128 matrices in frag layout
    const int seg = idx >> 14, r = idx & 16383;
    const int g = r >> 11, kc = (r >> 9) & 3, lane = (r >> 3) & 63, e = r & 7;
    const int k  = (kc<<5) + ((lane>>4)<<3) + e;
    const int nn = (g<<4) + (lane & 15);
    float v;
    switch (seg){
      case 0: v = iw1[k*HH + nn]; break;            // wi_a
      case 1: v = iw1[(HH+k)*HH + nn]; break;       // wi_b
      case 2: v = sw1[k*HH + nn]; break;
      case 3: v = sw2[k*HH + nn]; break;
      case 4: v = iw2[k*HH + nn]; break;
      case 5: v = uw2[k*HH + nn]; break;
      case 6: v = dw1[k*HH + nn]; break;
      case 7: v = ew2[k*HH + nn]; break;
      default: {                                     // DE = dw2 @ ew1 (fp32 product)
        float s = 0.f;
#pragma unroll
        for (int d=0; d<DD; ++d) s += dw2[k*DD + d] * ew1[d*HH + nn];
        v = s;
      } break;
    }
    hu hb; hb.h = (f16)v; ws[idx] = hb.u;
  } else if (idx < 180224){
    // uw1 (K=256) frag layout
    const int r = idx - 147456;
    const int g = r >> 12, kc = (r >> 9) & 7, lane = (r >> 3) & 63, e = r & 7;
    const int k  = (kc<<5) + ((lane>>4)<<3) + e;
    const int nn = (g<<4) + (lane & 15);
    hu hb; hb.h = (f16)uw1[k*HH + nn]; ws[idx] = hb.u;
  } else if (idx < 181248){
    const int r = idx - 180224, d = r >> 7, hcol = r & 127;   // dw2T [8][128]
    hu hb; hb.h = (f16)dw2[hcol*DD + d]; ws[idx] = hb.u;
  } else if (idx < 181376){
    const int nn = idx - 181248;                   // de_bias = db2 @ ew1 + eb1 (fp32)
    float v = eb1[nn];
#pragma unroll
    for (int d=0; d<DD; ++d) v += db2[d] * ew1[d*HH + nn];
    ((float*)ws)[90624 + nn] = v;
  }
}

// ---------------- rollout: 1 block / batch, 1024 threads (16 waves, 4 waves/SIMD) ----------------
// Counters showed the 512-thread version latency-bound at 2 waves/SIMD (MfmaUtil 3.5%,
// VALU 13%, both far from any roofline). 16 waves double the overlap capacity; weight
// B-frags (except wia/wib) are JIT-loaded per stage from wave-coalesced ws frags
// (waves w and w+8 read identical 1KB lines -> L1 hits). Whole pipeline f16
// (mfma_f32_16x16x32_f16, f32 accum): 1-instr cvt per LDS store vs 4-op bf16 RNE.
__global__ __launch_bounds__(1024, 4) void rollout_kernel(
    const float* __restrict__ gt, const int* __restrict__ rollout,
    const float* __restrict__ ew1, const float* __restrict__ eb1, const float* __restrict__ eb2,
    const float* __restrict__ sb1, const float* __restrict__ sb2,
    const float* __restrict__ ib1, const float* __restrict__ ib2,
    const float* __restrict__ ub1, const float* __restrict__ ub2,
    const float* __restrict__ db1, const float* __restrict__ db2,
    const u16* __restrict__ ws, float* __restrict__ out)
{
  extern __shared__ u16 smem[];
  u16 (*P)[LDP] = (u16(*)[LDP])smem;
  u16 (*Q)[LDP] = (u16(*)[LDP])(smem + KK*LDP);
  u16 (*R)[LDP] = (u16(*)[LDP])(smem + 2*KK*LDP);
  u16 (*S)[LDP] = (u16(*)[LDP])(smem + 3*KK*LDP);
  float* predbuf = (float*)S;                       // overlays S, only used at init

  const int tid = threadIdx.x, b = blockIdx.x;
  const int w = tid >> 6, lane = tid & 63;
  const int l15 = lane & 15, q = lane >> 4;
  const int wn = w & 7, wm = w >> 3;
  const int n = (wn << 4) + l15;

  int ns = rollout[0];
  if (ns > TT-1) ns = TT-1;
  if (ns > NSTEP) ns = NSTEP;
  if (ns < 0) ns = 0;

  // persistent stage1 weights only (8 frags = 32 VGPR) — keeps us under the 128-reg cap
  f16x8 F_WIA[4], F_WIB[4];
#pragma unroll
  for (int kc=0; kc<4; ++kc){
    F_WIA[kc] = *(const f16x8*)(ws + O_WIA + (wn<<11) + (kc<<9) + (lane<<3));
    F_WIB[kc] = *(const f16x8*)(ws + O_WIB + (wn<<11) + (kc<<9) + (lane<<3));
  }

  // per-thread bias registers (col n)
  const float eb2v = eb2[n], sb1v = sb1[n], sb2v = sb2[n];
  const float ib1v = ib1[n], ib2v = ib2[n];
  const float ub1v = ub1[n], ub2v = ub2[n], db1v = db1[n];
  const float dev  = ((const float*)ws)[90624 + n];
  const float db2v = db2[tid & 7];

  // init: targets copy + slots = enc(gt[:,0])
  for (int i=tid; i<NSTEP*KK*DD; i+=1024)
    out[PREDSZ + b*(NSTEP*KK*DD) + i] = gt[(size_t)b*(TT*KK*DD) + KK*DD + i];
  if (tid < KK*DD) predbuf[tid] = gt[(size_t)b*(TT*KK*DD) + tid];
  __syncthreads();
  mlp_in8(predbuf, ew1, eb1, Q, tid);
  __syncthreads();
  gemmJ<false>(Q, ws + O_EW2, 1.f, eb2v, P, wn, wm, l15, q, n, lane);   // P = slots
  __syncthreads();

  for (int t=0; t<ns; ++t){
    stage1(P, F_WIA, F_WIB, ws + O_SW1, ib1v, sb1v, Q, R, S, wn, wm, l15, q, n, lane);
    __syncthreads();
    interaction(Q, R, wn, wm, lane);                                     // Q = Ssum
    __syncthreads();
    gemmJ<false>(Q, ws + O_IW2, 1.f/64.f, ib2v, R, wn, wm, l15, q, n, lane); // R = delta_inter
    gemmJ<false>(S, ws + O_SW2, 1.f,      sb2v, P, wn, wm, l15, q, n, lane); // P = delta_self
    __syncthreads();
    gemm256J(P, R, ws + O_UW1, ub1v, Q, wn, wm, l15, q, n, lane);        // Q = relu([DS|DI]@uw1+ub1)
    __syncthreads();
    gemmJ<false>(Q, ws + O_UW2, 1.f, ub2v, P, wn, wm, l15, q, n, lane);  // P = new slots
    __syncthreads();
    gemmJ<true>(P, ws + O_DW1, 1.f, db1v, S, wn, wm, l15, q, n, lane);   // S = h_dec
    __syncthreads();
    gemmJ<true>(S, ws + O_DET, 1.f, dev, Q, wn, wm, l15, q, n, lane);    // Q = relu(S@DE+de_b)
    if (tid < 512) dec_out(S, ws + O_DW2T, db2v, out, b, t, tid);        // pred -> out (side)
    __syncthreads();
    gemmJ<false>(Q, ws + O_EW2, 1.f, eb2v, P, wn, wm, l15, q, n, lane);  // P = re-encoded slots
    __syncthreads();
  }
}

extern "C" void kernel_launch(void* const* d_in, const int* in_sizes, int n_in,
                              void* d_out, int out_size, void* d_ws, size_t ws_size,
                              hipStream_t stream)
{
  const float* gt  = (const float*)d_in[0];
  const int*   rs  = (const int*)d_in[1];
  const float* ew1 = (const float*)d_in[2];
  const float* eb1 = (const float*)d_in[3];
  const float* ew2 = (const float*)d_in[4];
  const float* eb2 = (const float*)d_in[5];
  const float* sw1 = (const float*)d_in[6];
  const float* sb1 = (const float*)d_in[7];
  const float* sw2 = (const float*)d_in[8];
  const float* sb2 = (const float*)d_in[9];
  const float* iw1 = (const float*)d_in[10];
  const float* ib1 = (const float*)d_in[11];
  const float* iw2 = (const float*)d_in[12];
  const float* ib2 = (const float*)d_in[13];
  const float* uw1 = (const float*)d_in[14];
  const float* ub1 = (const float*)d_in[15];
  const float* uw2 = (const float*)d_in[16];
  const float* ub2 = (const float*)d_in[17];
  const float* dw1 = (const float*)d_in[18];
  const float* db1 = (const float*)d_in[19];
  const float* dw2 = (const float*)d_in[20];
  const float* db2 = (const float*)d_in[21];
  float* out = (float*)d_out;
  u16*   ws  = (u16*)d_ws;

  const int smem_bytes = 4 * KK * LDP * (int)sizeof(u16);  // 69632
  (void)hipFuncSetAttribute((const void*)rollout_kernel,
                            hipFuncAttributeMaxDynamicSharedMemorySize, smem_bytes);

  hipLaunchKernelGGL(prep_kernel, dim3(709), dim3(256), 0, stream,
                     ew1, eb1, ew2, sw1, sw2, iw1, iw2, uw1, uw2, dw1, dw2, db2, ws);
  hipLaunchKernelGGL(rollout_kernel, dim3(BB), dim3(1024), smem_bytes, stream,
                     gt, rs, ew1, eb1, eb2, sb1, sb2, ib1, ib2, ub1, ub2,
                     db1, db2, ws, out);
}

// Round 3
// 206.581 us; speedup vs baseline: 1.2634x; 1.2634x over previous
//
#include <hip/hip_runtime.h>

// Problem constants
#define BB 128
#define TT 6
#define KK 64
#define DD 8
#define HH 128
#define NSTEP 5
#define LDP 136      // padded LDS row (u16 elems): 272B = 17*16B, 16B-aligned rows
#define PREDSZ (BB*NSTEP*KK*DD)   // 327680

typedef unsigned short u16;
typedef unsigned int   u32;
typedef _Float16 f16;
typedef __attribute__((ext_vector_type(8))) _Float16 f16x8;
typedef __attribute__((ext_vector_type(4))) float f32x4;
typedef __attribute__((ext_vector_type(2))) unsigned int u32x2;
typedef __attribute__((ext_vector_type(4))) unsigned int u32x4;
typedef __attribute__((ext_vector_type(2))) _Float16 h2;

union h2u { u32 u; h2 h; };
union hu  { u16 u; f16 h; };

__device__ __forceinline__ u16 f2h_bits(float f){
  hu v; v.h = (f16)f; return v.u;     // v_cvt_f16_f32, 1 instr
}

// ---------------- ws layout (u16 element offsets) ----------------
// Fused weight matrices (all exact fp32 products, cast f16), wave-coalesced frags:
//   FR[g=8][kc=4][lane=64][8] : elem off = g*2048 + kc*512 + lane*8
//   (one frag load = 64 lanes x 16B contiguous = 1KB coalesced)
// SUIU (K=256): FR[g=8][kc=8][lane=64][8], kc<4 = SU rows, kc>=4 = IU rows.
#define O_EWA   0        // ew2 @ wi_a
#define O_EWB   16384    // ew2 @ wi_b
#define O_EWS   32768    // ew2 @ self_w1
#define O_SUIU  49152    // [self_w2 @ uw1_top | (inter_w2 @ uw1_bot)/64]  (32768 elems)
#define O_UD    81920    // upd_w2 @ dec_w1
#define O_DET   98304    // dec_w2 @ enc_w1
#define O_DW2T  114688   // dw2 transposed f16 [8][128]
#define BIASF   57856    // float idx: bA,bB,bS,bU,bUD,deb  (6 x 128 f32)

// ---- GEMM: O(64x128) = A(64x128)@W [*1 + bias] ----
// 16 waves: wave w -> col group wn=w&7 (n = wn*16 + l15), m-half wm=w>>3 (2 m-tiles).
template<bool RELU>
__device__ __forceinline__ void gemmJ(const u16 (*A)[LDP], const u16* __restrict__ wt,
    float bias, u16 (*O)[LDP], int wn, int wm, int l15, int q, int n, int lane)
{
  f16x8 bf[4];
#pragma unroll
  for (int kc=0; kc<4; ++kc)
    bf[kc] = *(const f16x8*)(wt + (wn<<11) + (kc<<9) + (lane<<3));
#pragma unroll
  for (int mt=0; mt<2; ++mt){
    f32x4 acc = {0.f,0.f,0.f,0.f};
#pragma unroll
    for (int kc=0; kc<4; ++kc){
      f16x8 af = *(const f16x8*)&A[(wm<<5)+(mt<<4)+l15][(kc<<5)+(q<<3)];
      acc = __builtin_amdgcn_mfma_f32_16x16x32_f16(af, bf[kc], acc, 0,0,0);
    }
#pragma unroll
    for (int e=0; e<4; ++e){
      float v = acc[e] + bias;
      if (RELU) v = fmaxf(v, 0.f);
      O[(wm<<5)+(mt<<4)+(q<<2)+e][n] = f2h_bits(v);   // C/D: col=lane&15, row=q*4+e
    }
  }
}

// K=256: O = relu([A1 | A2] @ [SU|IU] + bU)
__device__ __forceinline__ void gemm256J(const u16 (*A1)[LDP], const u16 (*A2)[LDP],
    const u16* __restrict__ wt, float bias, u16 (*O)[LDP], int wn, int wm, int l15, int q, int n, int lane)
{
  f16x8 bf[8];
#pragma unroll
  for (int kc=0; kc<8; ++kc)
    bf[kc] = *(const f16x8*)(wt + (wn<<12) + (kc<<9) + (lane<<3));
#pragma unroll
  for (int mt=0; mt<2; ++mt){
    f32x4 acc = {0.f,0.f,0.f,0.f};
#pragma unroll
    for (int kc=0; kc<8; ++kc){
      const u16 (*As)[LDP] = (kc<4) ? A1 : A2;
      f16x8 af = *(const f16x8*)&As[(wm<<5)+(mt<<4)+l15][((kc&3)<<5)+(q<<3)];
      acc = __builtin_amdgcn_mfma_f32_16x16x32_f16(af, bf[kc], acc, 0,0,0);
    }
#pragma unroll
    for (int e=0; e<4; ++e){
      float v = fmaxf(acc[e] + bias, 0.f);
      O[(wm<<5)+(mt<<4)+(q<<2)+e][n] = f2h_bits(v);
    }
  }
}

// Fused stage1 on hidden h: one pass over A-frags feeds 3 GEMMs:
//   Q = h@EWA + bA (= slots@wia), R = h@EWB + bB (= slots@wib + ib1),
//   S = relu(h@EWS + bS) (= relu(slots@sw1 + sb1))
__device__ __forceinline__ void stage1J(const u16 (*P)[LDP],
    const u16* __restrict__ wa, const u16* __restrict__ wb, const u16* __restrict__ wsw,
    float bAv, float bBv, float bSv,
    u16 (*Q)[LDP], u16 (*R)[LDP], u16 (*S)[LDP],
    int wn, int wm, int l15, int q, int n, int lane)
{
  f16x8 fa[4], fb[4], fs[4];
#pragma unroll
  for (int kc=0; kc<4; ++kc){
    const int o = (wn<<11) + (kc<<9) + (lane<<3);
    fa[kc] = *(const f16x8*)(wa + o);
    fb[kc] = *(const f16x8*)(wb + o);
    fs[kc] = *(const f16x8*)(wsw + o);
  }
#pragma unroll
  for (int mt=0; mt<2; ++mt){
    f32x4 aA = {0.f,0.f,0.f,0.f}, aB = {0.f,0.f,0.f,0.f}, aS = {0.f,0.f,0.f,0.f};
#pragma unroll
    for (int kc=0; kc<4; ++kc){
      f16x8 af = *(const f16x8*)&P[(wm<<5)+(mt<<4)+l15][(kc<<5)+(q<<3)];
      aA = __builtin_amdgcn_mfma_f32_16x16x32_f16(af, fa[kc], aA, 0,0,0);
      aB = __builtin_amdgcn_mfma_f32_16x16x32_f16(af, fb[kc], aB, 0,0,0);
      aS = __builtin_amdgcn_mfma_f32_16x16x32_f16(af, fs[kc], aS, 0,0,0);
    }
#pragma unroll
    for (int e=0; e<4; ++e){
      const int row = (wm<<5)+(mt<<4)+(q<<2)+e;
      Q[row][n] = f2h_bits(aA[e]+bAv);
      R[row][n] = f2h_bits(aB[e]+bBv);
      S[row][n] = f2h_bits(fmaxf(aS[e]+bSv, 0.f));
    }
  }
}

// Qa := Ssum where Ssum[j,h] = sum_i relu(a[i,h]+b[j,h]); all f16.
// lanes=j; wave (wn,wm) owns 8 cols [wn*16+wm*8, +8): single b128 pass, in-place.
__device__ __forceinline__ void interaction(u16 (*Qa)[LDP], const u16 (*Rb)[LDP], int wn, int wm, int lane)
{
  const int h = (wn<<4) + (wm<<3);
  u32x4 bv = *(const u32x4*)&Rb[lane][h];
  h2u cb0, cb1, cb2, cb3; cb0.u = bv.x; cb1.u = bv.y; cb2.u = bv.z; cb3.u = bv.w;
  h2 z; z.x = (f16)0.f; z.y = (f16)0.f;
  h2 s0=z, s1=z, s2=z, s3=z, t0=z, t1=z, t2=z, t3=z;
#pragma unroll 8
  for (int i=0; i<KK; i+=2){
    u32x4 a0 = *(const u32x4*)&Qa[i][h];      // lane-uniform broadcast, 16B
    u32x4 a1 = *(const u32x4*)&Qa[i+1][h];
    h2u x0,x1,x2,x3, y0,y1,y2,y3;
    x0.u=a0.x; x1.u=a0.y; x2.u=a0.z; x3.u=a0.w;
    y0.u=a1.x; y1.u=a1.y; y2.u=a1.z; y3.u=a1.w;
    s0 += __builtin_elementwise_max(x0.h + cb0.h, z);
    s1 += __builtin_elementwise_max(x1.h + cb1.h, z);
    s2 += __builtin_elementwise_max(x2.h + cb2.h, z);
    s3 += __builtin_elementwise_max(x3.h + cb3.h, z);
    t0 += __builtin_elementwise_max(y0.h + cb0.h, z);
    t1 += __builtin_elementwise_max(y1.h + cb1.h, z);
    t2 += __builtin_elementwise_max(y2.h + cb2.h, z);
    t3 += __builtin_elementwise_max(y3.h + cb3.h, z);
  }
  s0 += t0; s1 += t1; s2 += t2; s3 += t3;
  h2u o0,o1,o2,o3; o0.h=s0; o1.h=s1; o2.h=s2; o3.h=s3;
  u32x4 ov; ov.x=o0.u; ov.y=o1.u; ov.z=o2.u; ov.w=o3.u;
  *(u32x4*)&Qa[lane][h] = ov;
}

// pred(64x8) = hd(64x128,f16) @ dw2 + db2 -> global out only (side branch, tid<512)
__device__ __forceinline__ void dec_out(const u16 (*S)[LDP], const u16* __restrict__ dwt,
    float db2v, float* __restrict__ out, int b, int t, int tid)
{
  const int r = tid>>3, d = tid&7;
  float acc = db2v;
#pragma unroll
  for (int c=0; c<16; ++c){
    f16x8 hv = *(const f16x8*)&S[r][c<<3];
    f16x8 wv = *(const f16x8*)(dwt + (d<<7) + (c<<3));
#pragma unroll
    for (int j=0; j<8; ++j)
      acc += (float)hv[j] * (float)wv[j];
  }
  out[(size_t)(b*NSTEP + t)*(KK*DD) + (r<<3) + d] = acc;
}

// h0 = relu(gt0 @ ew1 + eb1) — once at start (1024 threads: 8 rows each)
__device__ __forceinline__ void mlp_in8(const float* pred, const float* __restrict__ W,
    const float* __restrict__ bias, u16 (*O)[LDP], int tid)
{
  const int h = tid & 127, rg = tid >> 7;    // rg in [0,8)
  float wv[DD];
#pragma unroll
  for (int d=0; d<DD; ++d) wv[d] = W[d*HH + h];
  const float bv = bias[h];
  for (int rr=0; rr<8; ++rr){
    const int r = (rg<<3) + rr;
    float v = bv;
#pragma unroll
    for (int d=0; d<DD; ++d) v += pred[r*DD + d] * wv[d];
    O[r][h] = f2h_bits(fmaxf(v, 0.f));
  }
}

// ---------------- prep: fused fp32 weight products -> f16 frags ----------------
// EWA=ew2@wia  EWB=ew2@wib  EWS=ew2@sw1  SU=sw2@uw1_top  IU=(iw2@uw1_bot)/64
// UD=uw2@dw1   DET=dw2@ew1  + fused biases.
__global__ void prep_kernel(
    const float* __restrict__ ew1, const float* __restrict__ eb1,
    const float* __restrict__ ew2, const float* __restrict__ eb2,
    const float* __restrict__ sw1, const float* __restrict__ sb1,
    const float* __restrict__ sw2, const float* __restrict__ sb2,
    const float* __restrict__ iw1, const float* __restrict__ ib1,
    const float* __restrict__ iw2, const float* __restrict__ ib2,
    const float* __restrict__ uw1, const float* __restrict__ ub1,
    const float* __restrict__ uw2, const float* __restrict__ ub2,
    const float* __restrict__ dw1, const float* __restrict__ db1,
    const float* __restrict__ dw2, const float* __restrict__ db2,
    u16* __restrict__ ws)
{
  const int idx = blockIdx.x * 256 + threadIdx.x;
  if (idx < 49152){
    // EWA / EWB / EWS frags
    const int mat = idx >> 14, r = idx & 16383;
    const int g = r >> 11, kc = (r >> 9) & 3, lane = (r >> 3) & 63, e = r & 7;
    const int k  = (kc<<5) + ((lane>>4)<<3) + e;
    const int nn = (g<<4) + (lane & 15);
    float v = 0.f;
    if (mat == 0){ for (int m=0; m<HH; ++m) v += ew2[k*HH+m] * iw1[m*HH+nn]; }
    else if (mat == 1){ for (int m=0; m<HH; ++m) v += ew2[k*HH+m] * iw1[(HH+m)*HH+nn]; }
    else { for (int m=0; m<HH; ++m) v += ew2[k*HH+m] * sw1[m*HH+nn]; }
    hu hb; hb.h = (f16)v; ws[idx] = hb.u;
  } else if (idx < 81920){
    // SUIU (K=256) frags: kc<4 -> SU, kc>=4 -> IU/64
    const int r = idx - 49152;
    const int g = r >> 12, kc = (r >> 9) & 7, lane = (r >> 3) & 63, e = r & 7;
    const int k  = ((kc&3)<<5) + ((lane>>4)<<3) + e;
    const int nn = (g<<4) + (lane & 15);
    float v = 0.f;
    if (kc < 4){ for (int m=0; m<HH; ++m) v += sw2[k*HH+m] * uw1[m*HH+nn]; }
    else { for (int m=0; m<HH; ++m) v += iw2[k*HH+m] * uw1[(HH+m)*HH+nn]; v *= (1.f/64.f); }
    hu hb; hb.h = (f16)v; ws[idx] = hb.u;
  } else if (idx < 98304){
    // UD frags
    const int r = idx - 81920;
    const int g = r >> 11, kc = (r >> 9) & 3, lane = (r >> 3) & 63, e = r & 7;
    const int k  = (kc<<5) + ((lane>>4)<<3) + e;
    const int nn = (g<<4) + (lane & 15);
    float v = 0.f;
    for (int m=0; m<HH; ++m) v += uw2[k*HH+m] * dw1[m*HH+nn];
    hu hb; hb.h = (f16)v; ws[idx] = hb.u;
  } else if (idx < 114688){
    // DET frags: DE = dw2 @ ew1  (K=8 inner)
    const int r = idx - 98304;
    const int g = r >> 11, kc = (r >> 9) & 3, lane = (r >> 3) & 63, e = r & 7;
    const int k  = (kc<<5) + ((lane>>4)<<3) + e;
    const int nn = (g<<4) + (lane & 15);
    float v = 0.f;
#pragma unroll
    for (int d=0; d<DD; ++d) v += dw2[k*DD+d] * ew1[d*HH+nn];
    hu hb; hb.h = (f16)v; ws[idx] = hb.u;
  } else if (idx < 115712){
    const int r = idx - 114688, d = r >> 7, hcol = r & 127;   // dw2T [8][128]
    hu hb; hb.h = (f16)dw2[hcol*DD + d]; ws[idx] = hb.u;
  } else if (idx < 116480){
    // fused biases (f32)
    const int j = idx - 115712, which = j >> 7, nn = j & 127;
    float v = 0.f;
    switch (which){
      case 0: for (int m=0; m<HH; ++m) v += eb2[m] * iw1[m*HH+nn]; break;                  // bA
      case 1: for (int m=0; m<HH; ++m) v += eb2[m] * iw1[(HH+m)*HH+nn]; v += ib1[nn]; break; // bB
      case 2: for (int m=0; m<HH; ++m) v += eb2[m] * sw1[m*HH+nn]; v += sb1[nn]; break;    // bS
      case 3: for (int m=0; m<HH; ++m) v += sb2[m]*uw1[m*HH+nn] + ib2[m]*uw1[(HH+m)*HH+nn];
              v += ub1[nn]; break;                                                          // bU
      case 4: for (int m=0; m<HH; ++m) v += ub2[m] * dw1[m*HH+nn]; v += db1[nn]; break;    // bUD
      default:
#pragma unroll
        for (int d=0; d<DD; ++d) v += db2[d] * ew1[d*HH+nn];
        v += eb1[nn]; break;                                                                // deb
    }
    ((float*)ws)[BIASF + j] = v;
  }
}

// ---------------- rollout: 1 block / batch, 1024 threads, 5-stage fused loop ----------------
// All consecutive linear maps pre-multiplied at prep (exact fp32): the loop state is the
// pre-encoder hidden h, and each step is only:
//   stage1J (3 fused GEMMs) / interaction / gemm256 (SUIU) / UD / DET(+dec_out)
// = 5 barriers/step vs 9 in the unfused pipeline; 34% fewer MFMA FLOPs, ~45% fewer
// LDS A-frag reads. Counters showed the 9-stage version pinned at 166us regardless of
// occupancy/dtype/weight residency -> wall = sum of serialized lockstep phase costs.
__global__ __launch_bounds__(1024, 4) void rollout_kernel(
    const float* __restrict__ gt, const int* __restrict__ rollout,
    const float* __restrict__ ew1, const float* __restrict__ eb1,
    const float* __restrict__ db2,
    const u16* __restrict__ ws, float* __restrict__ out)
{
  extern __shared__ u16 smem[];
  u16 (*P)[LDP] = (u16(*)[LDP])smem;
  u16 (*Q)[LDP] = (u16(*)[LDP])(smem + KK*LDP);
  u16 (*R)[LDP] = (u16(*)[LDP])(smem + 2*KK*LDP);
  u16 (*S)[LDP] = (u16(*)[LDP])(smem + 3*KK*LDP);
  float* predbuf = (float*)S;                       // overlays S, only used at init

  const int tid = threadIdx.x, b = blockIdx.x;
  const int w = tid >> 6, lane = tid & 63;
  const int l15 = lane & 15, q = lane >> 4;
  const int wn = w & 7, wm = w >> 3;
  const int n = (wn << 4) + l15;

  int ns = rollout[0];
  if (ns > TT-1) ns = TT-1;
  if (ns > NSTEP) ns = NSTEP;
  if (ns < 0) ns = 0;

  // fused per-thread biases (col n)
  const float* bf32 = (const float*)ws;
  const float bAv  = bf32[BIASF + n];
  const float bBv  = bf32[BIASF + 128 + n];
  const float bSv  = bf32[BIASF + 256 + n];
  const float bUv  = bf32[BIASF + 384 + n];
  const float bUDv = bf32[BIASF + 512 + n];
  const float debv = bf32[BIASF + 640 + n];
  const float db2v = db2[tid & 7];

  // init: targets copy + h0 = relu(gt[:,0]@ew1 + eb1)
  for (int i=tid; i<NSTEP*KK*DD; i+=1024)
    out[PREDSZ + b*(NSTEP*KK*DD) + i] = gt[(size_t)b*(TT*KK*DD) + KK*DD + i];
  if (tid < KK*DD) predbuf[tid] = gt[(size_t)b*(TT*KK*DD) + tid];
  __syncthreads();
  mlp_in8(predbuf, ew1, eb1, P, tid);               // P = h
  __syncthreads();

  for (int t=0; t<ns; ++t){
    stage1J(P, ws+O_EWA, ws+O_EWB, ws+O_EWS, bAv, bBv, bSv,
            Q, R, S, wn, wm, l15, q, n, lane);      // Q=a, R=b(+ib1), S=hs
    __syncthreads();
    interaction(Q, R, wn, wm, lane);                // Q = Ssum
    __syncthreads();
    gemm256J(S, Q, ws+O_SUIU, bUv, R, wn, wm, l15, q, n, lane);  // R = hu
    __syncthreads();
    gemmJ<true>(R, ws+O_UD, bUDv, S, wn, wm, l15, q, n, lane);   // S = hd
    __syncthreads();
    gemmJ<true>(S, ws+O_DET, debv, P, wn, wm, l15, q, n, lane);  // P = h_next
    if (tid < 512) dec_out(S, ws+O_DW2T, db2v, out, b, t, tid);  // pred -> out (side)
    __syncthreads();
  }
}

extern "C" void kernel_launch(void* const* d_in, const int* in_sizes, int n_in,
                              void* d_out, int out_size, void* d_ws, size_t ws_size,
                              hipStream_t stream)
{
  const float* gt  = (const float*)d_in[0];
  const int*   rs  = (const int*)d_in[1];
  const float* ew1 = (const float*)d_in[2];
  const float* eb1 = (const float*)d_in[3];
  const float* ew2 = (const float*)d_in[4];
  const float* eb2 = (const float*)d_in[5];
  const float* sw1 = (const float*)d_in[6];
  const float* sb1 = (const float*)d_in[7];
  const float* sw2 = (const float*)d_in[8];
  const float* sb2 = (const float*)d_in[9];
  const float* iw1 = (const float*)d_in[10];
  const float* ib1 = (const float*)d_in[11];
  const float* iw2 = (const float*)d_in[12];
  const float* ib2 = (const float*)d_in[13];
  const float* uw1 = (const float*)d_in[14];
  const float* ub1 = (const float*)d_in[15];
  const float* uw2 = (const float*)d_in[16];
  const float* ub2 = (const float*)d_in[17];
  const float* dw1 = (const float*)d_in[18];
  const float* db1 = (const float*)d_in[19];
  const float* dw2 = (const float*)d_in[20];
  const float* db2 = (const float*)d_in[21];
  float* out = (float*)d_out;
  u16*   ws  = (u16*)d_ws;

  const int smem_bytes = 4 * KK * LDP * (int)sizeof(u16);  // 69632
  (void)hipFuncSetAttribute((const void*)rollout_kernel,
                            hipFuncAttributeMaxDynamicSharedMemorySize, smem_bytes);

  hipLaunchKernelGGL(prep_kernel, dim3(455), dim3(256), 0, stream,
                     ew1, eb1, ew2, eb2, sw1, sb1, sw2, sb2, iw1, ib1, iw2, ib2,
                     uw1, ub1, uw2, ub2, dw1, db1, dw2, db2, ws);
  hipLaunchKernelGGL(rollout_kernel, dim3(BB), dim3(1024), smem_bytes, stream,
                     gt, rs, ew1, eb1, db2, ws, out);
}

// Round 4
// 205.220 us; speedup vs baseline: 1.2718x; 1.0066x over previous
//
#include <hip/hip_runtime.h>

// Problem constants
#define BB 128
#define TT 6
#define KK 64
#define DD 8
#define HH 128
#define NSTEP 5
#define LDP 136      // padded LDS row (u16 elems): 272B = 17*16B, 16B-aligned rows
#define PREDSZ (BB*NSTEP*KK*DD)   // 327680

typedef unsigned short u16;
typedef unsigned int   u32;
typedef _Float16 f16;
typedef __attribute__((ext_vector_type(8))) _Float16 f16x8;
typedef __attribute__((ext_vector_type(4))) float f32x4;
typedef __attribute__((ext_vector_type(2))) unsigned int u32x2;
typedef __attribute__((ext_vector_type(4))) unsigned int u32x4;
typedef __attribute__((ext_vector_type(2))) _Float16 h2;

union h2u { u32 u; h2 h; };
union hu  { u16 u; f16 h; };

__device__ __forceinline__ u16 f2h_bits(float f){
  hu v; v.h = (f16)f; return v.u;     // v_cvt_f16_f32, 1 instr
}
__device__ __forceinline__ u32 pk2(float x, float y){  // two RNE cvts + pack
  hu a, b; a.h = (f16)x; b.h = (f16)y;
  return (u32)a.u | ((u32)b.u << 16);
}
__device__ __forceinline__ h2 u2h(u32 x){ h2u t; t.u = x; return t.h; }
__device__ __forceinline__ u32 h2u_(h2 x){ h2u t; t.h = x; return t.u; }

// ---------------- ws layout (u16 element offsets) ----------------
// Fused weight matrices (all exact fp32 products, cast f16), wave-coalesced frags:
//   FR[g=8][kc=4][lane=64][8] : elem off = g*2048 + kc*512 + lane*8
// SUIU (K=256): FR[g=8][kc=8][lane=64][8], kc<4 = SU rows, kc>=4 = IU rows.
#define O_EWA   0        // ew2 @ wi_a
#define O_EWB   16384    // ew2 @ wi_b
#define O_EWS   32768    // ew2 @ self_w1
#define O_SUIU  49152    // [self_w2 @ uw1_top | (inter_w2 @ uw1_bot)/64]  (32768 elems)
#define O_UD    81920    // upd_w2 @ dec_w1
#define O_DET   98304    // dec_w2 @ enc_w1
#define O_DW2T  114688   // dw2 transposed f16 [8][128]
#define BIASF   57856    // float idx: bA,bB,bS,bU,bUD,deb  (6 x 128 f32)

// ---- GEMM: O(64x128) = A(64x128)@W [+ bias] ----
// 16 waves: wave w -> col group wn=w&7 (n = wn*16 + l15), m-half wm=w>>3 (2 m-tiles).
template<bool RELU>
__device__ __forceinline__ void gemmJ(const u16 (*A)[LDP], const u16* __restrict__ wt,
    float bias, u16 (*O)[LDP], int wn, int wm, int l15, int q, int n, int lane)
{
  f16x8 bf[4];
#pragma unroll
  for (int kc=0; kc<4; ++kc)
    bf[kc] = *(const f16x8*)(wt + (wn<<11) + (kc<<9) + (lane<<3));
#pragma unroll
  for (int mt=0; mt<2; ++mt){
    f32x4 acc = {0.f,0.f,0.f,0.f};
#pragma unroll
    for (int kc=0; kc<4; ++kc){
      f16x8 af = *(const f16x8*)&A[(wm<<5)+(mt<<4)+l15][(kc<<5)+(q<<3)];
      acc = __builtin_amdgcn_mfma_f32_16x16x32_f16(af, bf[kc], acc, 0,0,0);
    }
#pragma unroll
    for (int e=0; e<4; ++e){
      float v = acc[e] + bias;
      if (RELU) v = fmaxf(v, 0.f);
      O[(wm<<5)+(mt<<4)+(q<<2)+e][n] = f2h_bits(v);   // C/D: col=lane&15, row=q*4+e
    }
  }
}

// K=256: O = relu([A1 | A2] @ [SU|IU] + bU)
__device__ __forceinline__ void gemm256J(const u16 (*A1)[LDP], const u16 (*A2)[LDP],
    const u16* __restrict__ wt, float bias, u16 (*O)[LDP], int wn, int wm, int l15, int q, int n, int lane)
{
  f16x8 bf[8];
#pragma unroll
  for (int kc=0; kc<8; ++kc)
    bf[kc] = *(const f16x8*)(wt + (wn<<12) + (kc<<9) + (lane<<3));
#pragma unroll
  for (int mt=0; mt<2; ++mt){
    f32x4 acc = {0.f,0.f,0.f,0.f};
#pragma unroll
    for (int kc=0; kc<8; ++kc){
      const u16 (*As)[LDP] = (kc<4) ? A1 : A2;
      f16x8 af = *(const f16x8*)&As[(wm<<5)+(mt<<4)+l15][((kc&3)<<5)+(q<<3)];
      acc = __builtin_amdgcn_mfma_f32_16x16x32_f16(af, bf[kc], acc, 0,0,0);
    }
#pragma unroll
    for (int e=0; e<4; ++e){
      float v = fmaxf(acc[e] + bias, 0.f);
      O[(wm<<5)+(mt<<4)+(q<<2)+e][n] = f2h_bits(v);
    }
  }
}

// ---- Fused stage1 + interaction: ONE barrier interval instead of two ----
// Wave (wn,wm) computes a,b = h@EWA/EWB (+biases) for ALL 64 rows x its 16 cols
// (4 m-tiles, duplicated across the wm pair -> a,b never touch LDS), plus
// hs = relu(h@EWS+bS) for its own wm-half (written to S). Then the interaction
//   Ssum[j,n] = sum_i relu(a[i,n]+b[j,n])
// is column-local: col n's 64 a,b values live in the 4 q-threads of lane group l15.
// Wave wm handles j in [wm*32, wm*32+32): gather the 32 b's via __shfl, accumulate
// 16 own-i partials in pk-f16, shfl_xor-reduce over q, store Ssum to Q.
__device__ __forceinline__ void fusedS1I(const u16 (*P)[LDP], const u16* __restrict__ ws,
    float bAv, float bBv, float bSv,
    u16 (*Q)[LDP], u16 (*S)[LDP],
    int wn, int wm, int l15, int q, int n, int lane)
{
  f16x8 fa[4], fb[4], fs[4];
#pragma unroll
  for (int kc=0; kc<4; ++kc){
    const int o = (wn<<11) + (kc<<9) + (lane<<3);
    fa[kc] = *(const f16x8*)(ws + O_EWA + o);
    fb[kc] = *(const f16x8*)(ws + O_EWB + o);
    fs[kc] = *(const f16x8*)(ws + O_EWS + o);
  }
  u32 aPk[4][2], bPk[4][2];   // [mt][e-pair]: rows mt*16+q*4+{2p,2p+1}, col n
#pragma unroll
  for (int mt=0; mt<4; ++mt){
    f16x8 af[4];
#pragma unroll
    for (int kc=0; kc<4; ++kc)
      af[kc] = *(const f16x8*)&P[(mt<<4)+l15][(kc<<5)+(q<<3)];
    f32x4 aA = {0.f,0.f,0.f,0.f}, aB = {0.f,0.f,0.f,0.f};
#pragma unroll
    for (int kc=0; kc<4; ++kc){
      aA = __builtin_amdgcn_mfma_f32_16x16x32_f16(af[kc], fa[kc], aA, 0,0,0);
      aB = __builtin_amdgcn_mfma_f32_16x16x32_f16(af[kc], fb[kc], aB, 0,0,0);
    }
    aPk[mt][0] = pk2(aA[0]+bAv, aA[1]+bAv);
    aPk[mt][1] = pk2(aA[2]+bAv, aA[3]+bAv);
    bPk[mt][0] = pk2(aB[0]+bBv, aB[1]+bBv);
    bPk[mt][1] = pk2(aB[2]+bBv, aB[3]+bBv);
    if ((mt>>1) == wm){                      // hs for own m-half only
      f32x4 hA = {0.f,0.f,0.f,0.f};
#pragma unroll
      for (int kc=0; kc<4; ++kc)
        hA = __builtin_amdgcn_mfma_f32_16x16x32_f16(af[kc], fs[kc], hA, 0,0,0);
#pragma unroll
      for (int e=0; e<4; ++e)
        S[(mt<<4)+(q<<2)+e][n] = f2h_bits(fmaxf(hA[e]+bSv, 0.f));
    }
  }

  // ---- in-register interaction (no barrier: wave-local) ----
  // b-table for this wave's j-range, indexed by ABSOLUTE q' slot.
  const u32 b0 = bPk[(wm<<1)][0],   b1 = bPk[(wm<<1)][1];
  const u32 b2 = bPk[(wm<<1)+1][0], b3 = bPk[(wm<<1)+1][1];
  u32 jt[4][4];
#pragma unroll
  for (int qp=0; qp<4; ++qp){
    const int src = (qp<<4) + l15;
    jt[qp][0] = (u32)__shfl((int)b0, src);
    jt[qp][1] = (u32)__shfl((int)b1, src);
    jt[qp][2] = (u32)__shfl((int)b2, src);
    jt[qp][3] = (u32)__shfl((int)b3, src);
  }
  h2 z; z.x = (f16)0.f; z.y = (f16)0.f;
  h2 s[4][4];
#pragma unroll
  for (int qp=0; qp<4; ++qp)
#pragma unroll
    for (int X=0; X<4; ++X) s[qp][X] = z;
  // accumulate partials over this thread's 16 i-values
#pragma unroll
  for (int mt=0; mt<4; ++mt)
#pragma unroll
    for (int p=0; p<2; ++p){
      const u32 ap = aPk[mt][p];
      const h2 hl = u2h(__builtin_amdgcn_perm(ap, ap, 0x01000100));  // lo f16 dup
      const h2 hh = u2h(__builtin_amdgcn_perm(ap, ap, 0x03020302));  // hi f16 dup
#pragma unroll
      for (int qp=0; qp<4; ++qp)
#pragma unroll
        for (int X=0; X<4; ++X){
          const h2 bt = u2h(jt[qp][X]);
          s[qp][X] += __builtin_elementwise_max(hl + bt, z);
          s[qp][X] += __builtin_elementwise_max(hh + bt, z);
        }
    }
  // reduce over the 4 q-threads (lanes l15, l15+16, l15+32, l15+48)
#pragma unroll
  for (int m=0; m<2; ++m){
    const int msk = 16 << m;
#pragma unroll
    for (int qp=0; qp<4; ++qp)
#pragma unroll
      for (int X=0; X<4; ++X)
        s[qp][X] += u2h((u32)__shfl_xor((int)h2u_(s[qp][X]), msk));
  }
  // write own q-slot: j = wm*32 + mh*16 + q*4 + 2p + {0,1}
#pragma unroll
  for (int qp=0; qp<4; ++qp) if (qp == q){
#pragma unroll
    for (int X=0; X<4; ++X){
      const int mh = X>>1, p = X&1;
      const int j = (wm<<5) + (mh<<4) + (qp<<2) + (p<<1);
      hu lo, hi; lo.h = s[qp][X].x; hi.h = s[qp][X].y;
      Q[j][n]   = lo.u;
      Q[j+1][n] = hi.u;
    }
  }
}

// pred(64x8) = hd(64x128,f16) @ dw2 + db2 -> global out only (side branch, tid<512)
__device__ __forceinline__ void dec_out(const u16 (*S)[LDP], const u16* __restrict__ dwt,
    float db2v, float* __restrict__ out, int b, int t, int tid)
{
  const int r = tid>>3, d = tid&7;
  float acc = db2v;
#pragma unroll
  for (int c=0; c<16; ++c){
    f16x8 hv = *(const f16x8*)&S[r][c<<3];
    f16x8 wv = *(const f16x8*)(dwt + (d<<7) + (c<<3));
#pragma unroll
    for (int j=0; j<8; ++j)
      acc += (float)hv[j] * (float)wv[j];
  }
  out[(size_t)(b*NSTEP + t)*(KK*DD) + (r<<3) + d] = acc;
}

// h0 = relu(gt0 @ ew1 + eb1) — once at start (1024 threads: 8 rows each)
__device__ __forceinline__ void mlp_in8(const float* pred, const float* __restrict__ W,
    const float* __restrict__ bias, u16 (*O)[LDP], int tid)
{
  const int h = tid & 127, rg = tid >> 7;    // rg in [0,8)
  float wv[DD];
#pragma unroll
  for (int d=0; d<DD; ++d) wv[d] = W[d*HH + h];
  const float bv = bias[h];
  for (int rr=0; rr<8; ++rr){
    const int r = (rg<<3) + rr;
    float v = bv;
#pragma unroll
    for (int d=0; d<DD; ++d) v += pred[r*DD + d] * wv[d];
    O[r][h] = f2h_bits(fmaxf(v, 0.f));
  }
}

// ---------------- prep: fused fp32 weight products -> f16 frags ----------------
// EWA=ew2@wia  EWB=ew2@wib  EWS=ew2@sw1  SU=sw2@uw1_top  IU=(iw2@uw1_bot)/64
// UD=uw2@dw1   DET=dw2@ew1  + fused biases.
__global__ void prep_kernel(
    const float* __restrict__ ew1, const float* __restrict__ eb1,
    const float* __restrict__ ew2, const float* __restrict__ eb2,
    const float* __restrict__ sw1, const float* __restrict__ sb1,
    const float* __restrict__ sw2, const float* __restrict__ sb2,
    const float* __restrict__ iw1, const float* __restrict__ ib1,
    const float* __restrict__ iw2, const float* __restrict__ ib2,
    const float* __restrict__ uw1, const float* __restrict__ ub1,
    const float* __restrict__ uw2, const float* __restrict__ ub2,
    const float* __restrict__ dw1, const float* __restrict__ db1,
    const float* __restrict__ dw2, const float* __restrict__ db2,
    u16* __restrict__ ws)
{
  const int idx = blockIdx.x * 256 + threadIdx.x;
  if (idx < 49152){
    // EWA / EWB / EWS frags
    const int mat = idx >> 14, r = idx & 16383;
    const int g = r >> 11, kc = (r >> 9) & 3, lane = (r >> 3) & 63, e = r & 7;
    const int k  = (kc<<5) + ((lane>>4)<<3) + e;
    const int nn = (g<<4) + (lane & 15);
    float v = 0.f;
    if (mat == 0){ for (int m=0; m<HH; ++m) v += ew2[k*HH+m] * iw1[m*HH+nn]; }
    else if (mat == 1){ for (int m=0; m<HH; ++m) v += ew2[k*HH+m] * iw1[(HH+m)*HH+nn]; }
    else { for (int m=0; m<HH; ++m) v += ew2[k*HH+m] * sw1[m*HH+nn]; }
    hu hb; hb.h = (f16)v; ws[idx] = hb.u;
  } else if (idx < 81920){
    // SUIU (K=256) frags: kc<4 -> SU, kc>=4 -> IU/64
    const int r = idx - 49152;
    const int g = r >> 12, kc = (r >> 9) & 7, lane = (r >> 3) & 63, e = r & 7;
    const int k  = ((kc&3)<<5) + ((lane>>4)<<3) + e;
    const int nn = (g<<4) + (lane & 15);
    float v = 0.f;
    if (kc < 4){ for (int m=0; m<HH; ++m) v += sw2[k*HH+m] * uw1[m*HH+nn]; }
    else { for (int m=0; m<HH; ++m) v += iw2[k*HH+m] * uw1[(HH+m)*HH+nn]; v *= (1.f/64.f); }
    hu hb; hb.h = (f16)v; ws[idx] = hb.u;
  } else if (idx < 98304){
    // UD frags
    const int r = idx - 81920;
    const int g = r >> 11, kc = (r >> 9) & 3, lane = (r >> 3) & 63, e = r & 7;
    const int k  = (kc<<5) + ((lane>>4)<<3) + e;
    const int nn = (g<<4) + (lane & 15);
    float v = 0.f;
    for (int m=0; m<HH; ++m) v += uw2[k*HH+m] * dw1[m*HH+nn];
    hu hb; hb.h = (f16)v; ws[idx] = hb.u;
  } else if (idx < 114688){
    // DET frags: DE = dw2 @ ew1  (K=8 inner)
    const int r = idx - 98304;
    const int g = r >> 11, kc = (r >> 9) & 3, lane = (r >> 3) & 63, e = r & 7;
    const int k  = (kc<<5) + ((lane>>4)<<3) + e;
    const int nn = (g<<4) + (lane & 15);
    float v = 0.f;
#pragma unroll
    for (int d=0; d<DD; ++d) v += dw2[k*DD+d] * ew1[d*HH+nn];
    hu hb; hb.h = (f16)v; ws[idx] = hb.u;
  } else if (idx < 115712){
    const int r = idx - 114688, d = r >> 7, hcol = r & 127;   // dw2T [8][128]
    hu hb; hb.h = (f16)dw2[hcol*DD + d]; ws[idx] = hb.u;
  } else if (idx < 116480){
    // fused biases (f32)
    const int j = idx - 115712, which = j >> 7, nn = j & 127;
    float v = 0.f;
    switch (which){
      case 0: for (int m=0; m<HH; ++m) v += eb2[m] * iw1[m*HH+nn]; break;                  // bA
      case 1: for (int m=0; m<HH; ++m) v += eb2[m] * iw1[(HH+m)*HH+nn]; v += ib1[nn]; break; // bB
      case 2: for (int m=0; m<HH; ++m) v += eb2[m] * sw1[m*HH+nn]; v += sb1[nn]; break;    // bS
      case 3: for (int m=0; m<HH; ++m) v += sb2[m]*uw1[m*HH+nn] + ib2[m]*uw1[(HH+m)*HH+nn];
              v += ub1[nn]; break;                                                          // bU
      case 4: for (int m=0; m<HH; ++m) v += ub2[m] * dw1[m*HH+nn]; v += db1[nn]; break;    // bUD
      default:
#pragma unroll
        for (int d=0; d<DD; ++d) v += db2[d] * ew1[d*HH+nn];
        v += eb1[nn]; break;                                                                // deb
    }
    ((float*)ws)[BIASF + j] = v;
  }
}

// ---------------- rollout: 1 block / batch, 1024 threads, 4-interval fused loop ----------------
// Measured law across rounds: wall = #barrier-intervals x ~4us (9 stages=166us, 5=100us,
// invariant to occupancy/dtype/weight residency). This round removes the stage1->interaction
// barrier: interaction is column-local, so each wave computes full-height a,b for its 16 cols
// in registers (duplicated MFMA across the wm pair; MfmaUtil was 3.5% -> headroom) and runs
// the interaction wave-locally via __shfl. 4 intervals/step: s1+inter / g256 / UD / DET+dec.
__global__ __launch_bounds__(1024, 4) void rollout_kernel(
    const float* __restrict__ gt, const int* __restrict__ rollout,
    const float* __restrict__ ew1, const float* __restrict__ eb1,
    const float* __restrict__ db2,
    const u16* __restrict__ ws, float* __restrict__ out)
{
  extern __shared__ u16 smem[];
  u16 (*P)[LDP] = (u16(*)[LDP])smem;
  u16 (*Q)[LDP] = (u16(*)[LDP])(smem + KK*LDP);
  u16 (*R)[LDP] = (u16(*)[LDP])(smem + 2*KK*LDP);
  u16 (*S)[LDP] = (u16(*)[LDP])(smem + 3*KK*LDP);
  float* predbuf = (float*)S;                       // overlays S, only used at init

  const int tid = threadIdx.x, b = blockIdx.x;
  const int w = tid >> 6, lane = tid & 63;
  const int l15 = lane & 15, q = lane >> 4;
  const int wn = w & 7, wm = w >> 3;
  const int n = (wn << 4) + l15;

  int ns = rollout[0];
  if (ns > TT-1) ns = TT-1;
  if (ns > NSTEP) ns = NSTEP;
  if (ns < 0) ns = 0;

  // fused per-thread biases (col n)
  const float* bf32 = (const float*)ws;
  const float bAv  = bf32[BIASF + n];
  const float bBv  = bf32[BIASF + 128 + n];
  const float bSv  = bf32[BIASF + 256 + n];
  const float bUv  = bf32[BIASF + 384 + n];
  const float bUDv = bf32[BIASF + 512 + n];
  const float debv = bf32[BIASF + 640 + n];
  const float db2v = db2[tid & 7];

  // init: targets copy + h0 = relu(gt[:,0]@ew1 + eb1)
  for (int i=tid; i<NSTEP*KK*DD; i+=1024)
    out[PREDSZ + b*(NSTEP*KK*DD) + i] = gt[(size_t)b*(TT*KK*DD) + KK*DD + i];
  if (tid < KK*DD) predbuf[tid] = gt[(size_t)b*(TT*KK*DD) + tid];
  __syncthreads();
  mlp_in8(predbuf, ew1, eb1, P, tid);               // P = h
  __syncthreads();

  for (int t=0; t<ns; ++t){
    fusedS1I(P, ws, bAv, bBv, bSv, Q, S, wn, wm, l15, q, n, lane);  // Q=Ssum, S=hs
    __syncthreads();
    gemm256J(S, Q, ws+O_SUIU, bUv, R, wn, wm, l15, q, n, lane);  // R = hu
    __syncthreads();
    gemmJ<true>(R, ws+O_UD, bUDv, S, wn, wm, l15, q, n, lane);   // S = hd
    __syncthreads();
    gemmJ<true>(S, ws+O_DET, debv, P, wn, wm, l15, q, n, lane);  // P = h_next
    if (tid < 512) dec_out(S, ws+O_DW2T, db2v, out, b, t, tid);  // pred -> out (side)
    __syncthreads();
  }
}

extern "C" void kernel_launch(void* const* d_in, const int* in_sizes, int n_in,
                              void* d_out, int out_size, void* d_ws, size_t ws_size,
                              hipStream_t stream)
{
  const float* gt  = (const float*)d_in[0];
  const int*   rs  = (const int*)d_in[1];
  const float* ew1 = (const float*)d_in[2];
  const float* eb1 = (const float*)d_in[3];
  const float* ew2 = (const float*)d_in[4];
  const float* eb2 = (const float*)d_in[5];
  const float* sw1 = (const float*)d_in[6];
  const float* sb1 = (const float*)d_in[7];
  const float* sw2 = (const float*)d_in[8];
  const float* sb2 = (const float*)d_in[9];
  const float* iw1 = (const float*)d_in[10];
  const float* ib1 = (const float*)d_in[11];
  const float* iw2 = (const float*)d_in[12];
  const float* ib2 = (const float*)d_in[13];
  const float* uw1 = (const float*)d_in[14];
  const float* ub1 = (const float*)d_in[15];
  const float* uw2 = (const float*)d_in[16];
  const float* ub2 = (const float*)d_in[17];
  const float* dw1 = (const float*)d_in[18];
  const float* db1 = (const float*)d_in[19];
  const float* dw2 = (const float*)d_in[20];
  const float* db2 = (const float*)d_in[21];
  float* out = (float*)d_out;
  u16*   ws  = (u16*)d_ws;

  const int smem_bytes = 4 * KK * LDP * (int)sizeof(u16);  // 69632
  (void)hipFuncSetAttribute((const void*)rollout_kernel,
                            hipFuncAttributeMaxDynamicSharedMemorySize, smem_bytes);

  hipLaunchKernelGGL(prep_kernel, dim3(455), dim3(256), 0, stream,
                     ew1, eb1, ew2, eb2, sw1, sb1, sw2, sb2, iw1, ib1, iw2, ib2,
                     uw1, ub1, uw2, ub2, dw1, db1, dw2, db2, ws);
  hipLaunchKernelGGL(rollout_kernel, dim3(BB), dim3(1024), smem_bytes, stream,
                     gt, rs, ew1, eb1, db2, ws, out);
}

// Round 5
// 198.290 us; speedup vs baseline: 1.3162x; 1.0349x over previous
//
#include <hip/hip_runtime.h>

// Problem constants
#define BB 128
#define TT 6
#define KK 64
#define DD 8
#define HH 128
#define NSTEP 5
#define LDP 136      // padded LDS row (u16 elems): 272B = 17*16B, 16B-aligned rows
#define PREDSZ (BB*NSTEP*KK*DD)   // 327680

typedef unsigned short u16;
typedef unsigned int   u32;
typedef _Float16 f16;
typedef __attribute__((ext_vector_type(8))) _Float16 f16x8;
typedef __attribute__((ext_vector_type(4))) float f32x4;
typedef __attribute__((ext_vector_type(2))) unsigned int u32x2;
typedef __attribute__((ext_vector_type(4))) unsigned int u32x4;
typedef __attribute__((ext_vector_type(2))) _Float16 h2;

union h2u { u32 u; h2 h; };
union hu  { u16 u; f16 h; };

__device__ __forceinline__ u16 f2h_bits(float f){
  hu v; v.h = (f16)f; return v.u;     // v_cvt_f16_f32, 1 instr
}
__device__ __forceinline__ u32 pk2(float x, float y){  // two RNE cvts + pack
  hu a, b; a.h = (f16)x; b.h = (f16)y;
  return (u32)a.u | ((u32)b.u << 16);
}
__device__ __forceinline__ h2 u2h(u32 x){ h2u t; t.u = x; return t.h; }
__device__ __forceinline__ u32 h2u_(h2 x){ h2u t; t.h = x; return t.u; }

// ---------------- ws layout (u16 element offsets) ----------------
// Fused weight matrices (all exact fp32 products, cast f16), wave-coalesced frags:
//   FR[g=8][kc=4][lane=64][8] : elem off = g*2048 + kc*512 + lane*8
// SUIU (K=256): FR[g=8][kc=8][lane=64][8], kc<4 = SU rows, kc>=4 = IU rows.
#define O_EWA   0        // ew2 @ wi_a
#define O_EWB   16384    // ew2 @ wi_b
#define O_EWS   32768    // ew2 @ self_w1
#define O_SUIU  49152    // [self_w2 @ uw1_top | (inter_w2 @ uw1_bot)/64]  (32768 elems)
#define O_UD    81920    // upd_w2 @ dec_w1
#define O_DET   98304    // dec_w2 @ enc_w1
#define O_DW2T  114688   // dw2 transposed f16 [8][128]
#define BIASF   57856    // float idx: bA,bB,bS,bU,bUD,deb  (6 x 128 f32)
// pair-exchange region:
#define O_XBUF  131072                    // u16: [batch][half][parity][4096]
#define O_FLAG  (O_XBUF + 128*2*2*4096)   // u16 offset of u32 flags[128][2][2]
// total ws need ~ 4.26 MB

// ---- half-GEMM: O(32x128) = A(32x128)@W [+ bias], 8 waves, wave wn -> 16 cols, 2 m-tiles ----
template<bool RELU>
__device__ __forceinline__ void gemmH(const u16 (*A)[LDP], const u16* __restrict__ wt,
    float bias, u16 (*O)[LDP], int wn, int l15, int q, int n, int lane)
{
  f16x8 bf[4];
#pragma unroll
  for (int kc=0; kc<4; ++kc)
    bf[kc] = *(const f16x8*)(wt + (wn<<11) + (kc<<9) + (lane<<3));
#pragma unroll
  for (int mt=0; mt<2; ++mt){
    f32x4 acc = {0.f,0.f,0.f,0.f};
#pragma unroll
    for (int kc=0; kc<4; ++kc){
      f16x8 af = *(const f16x8*)&A[(mt<<4)+l15][(kc<<5)+(q<<3)];
      acc = __builtin_amdgcn_mfma_f32_16x16x32_f16(af, bf[kc], acc, 0,0,0);
    }
#pragma unroll
    for (int e=0; e<4; ++e){
      float v = acc[e] + bias;
      if (RELU) v = fmaxf(v, 0.f);
      O[(mt<<4)+(q<<2)+e][n] = f2h_bits(v);   // C/D: col=lane&15, row=q*4+e
    }
  }
}

// K=256: O(32x128) = relu([A1 | A2] @ [SU|IU] + bU), A1/A2 32 local rows each
__device__ __forceinline__ void gemm256H(const u16 (*A1)[LDP], const u16 (*A2)[LDP],
    const u16* __restrict__ wt, float bias, u16 (*O)[LDP], int wn, int l15, int q, int n, int lane)
{
  f16x8 bf[8];
#pragma unroll
  for (int kc=0; kc<8; ++kc)
    bf[kc] = *(const f16x8*)(wt + (wn<<12) + (kc<<9) + (lane<<3));
#pragma unroll
  for (int mt=0; mt<2; ++mt){
    f32x4 acc = {0.f,0.f,0.f,0.f};
#pragma unroll
    for (int kc=0; kc<8; ++kc){
      const u16 (*As)[LDP] = (kc<4) ? A1 : A2;
      f16x8 af = *(const f16x8*)&As[(mt<<4)+l15][((kc&3)<<5)+(q<<3)];
      acc = __builtin_amdgcn_mfma_f32_16x16x32_f16(af, bf[kc], acc, 0,0,0);
    }
#pragma unroll
    for (int e=0; e<4; ++e){
      float v = fmaxf(acc[e] + bias, 0.f);
      O[(mt<<4)+(q<<2)+e][n] = f2h_bits(v);
    }
  }
}

// ---- Fused stage1 + interaction, pair-split version ----
// Block (batch, half) holds FULL h (64 rows) in P. Wave wn computes a,b = h@EWA/EWB
// for ALL 64 rows x its 16 cols in registers (4 m-tiles), hs = relu(h@EWS+bS) for the
// block's half rows only -> S(32 local rows). Interaction handled for the block's own
// j-half (j in [half*32, half*32+32)) entirely wave-locally; Ssum -> Q (32 local rows).
__device__ __forceinline__ void fusedS1I(const u16 (*P)[LDP], const u16* __restrict__ ws,
    float bAv, float bBv, float bSv,
    u16 (*Q)[LDP], u16 (*S)[LDP],
    int wn, int half, int l15, int q, int n, int lane)
{
  f16x8 fa[4], fb[4], fs[4];
#pragma unroll
  for (int kc=0; kc<4; ++kc){
    const int o = (wn<<11) + (kc<<9) + (lane<<3);
    fa[kc] = *(const f16x8*)(ws + O_EWA + o);
    fb[kc] = *(const f16x8*)(ws + O_EWB + o);
    fs[kc] = *(const f16x8*)(ws + O_EWS + o);
  }
  u32 aPk[4][2], bPk[4][2];   // [mt][e-pair]: rows mt*16+q*4+{2p,2p+1}, col n
#pragma unroll
  for (int mt=0; mt<4; ++mt){
    f16x8 af[4];
#pragma unroll
    for (int kc=0; kc<4; ++kc)
      af[kc] = *(const f16x8*)&P[(mt<<4)+l15][(kc<<5)+(q<<3)];
    f32x4 aA = {0.f,0.f,0.f,0.f}, aB = {0.f,0.f,0.f,0.f};
#pragma unroll
    for (int kc=0; kc<4; ++kc){
      aA = __builtin_amdgcn_mfma_f32_16x16x32_f16(af[kc], fa[kc], aA, 0,0,0);
      aB = __builtin_amdgcn_mfma_f32_16x16x32_f16(af[kc], fb[kc], aB, 0,0,0);
    }
    aPk[mt][0] = pk2(aA[0]+bAv, aA[1]+bAv);
    aPk[mt][1] = pk2(aA[2]+bAv, aA[3]+bAv);
    bPk[mt][0] = pk2(aB[0]+bBv, aB[1]+bBv);
    bPk[mt][1] = pk2(aB[2]+bBv, aB[3]+bBv);
    if ((mt>>1) == half){                    // hs for own half rows -> local S
      f32x4 hA = {0.f,0.f,0.f,0.f};
#pragma unroll
      for (int kc=0; kc<4; ++kc)
        hA = __builtin_amdgcn_mfma_f32_16x16x32_f16(af[kc], fs[kc], hA, 0,0,0);
#pragma unroll
      for (int e=0; e<4; ++e)
        S[((mt&1)<<4)+(q<<2)+e][n] = f2h_bits(fmaxf(hA[e]+bSv, 0.f));
    }
  }

  // ---- in-register interaction for own j-half (no barrier: wave-local) ----
  const u32 b0 = bPk[(half<<1)][0],   b1 = bPk[(half<<1)][1];
  const u32 b2 = bPk[(half<<1)+1][0], b3 = bPk[(half<<1)+1][1];
  u32 jt[4][4];
#pragma unroll
  for (int qp=0; qp<4; ++qp){
    const int src = (qp<<4) + l15;
    jt[qp][0] = (u32)__shfl((int)b0, src);
    jt[qp][1] = (u32)__shfl((int)b1, src);
    jt[qp][2] = (u32)__shfl((int)b2, src);
    jt[qp][3] = (u32)__shfl((int)b3, src);
  }
  h2 z; z.x = (f16)0.f; z.y = (f16)0.f;
  h2 s[4][4];
#pragma unroll
  for (int qp=0; qp<4; ++qp)
#pragma unroll
    for (int X=0; X<4; ++X) s[qp][X] = z;
#pragma unroll
  for (int mt=0; mt<4; ++mt)
#pragma unroll
    for (int p=0; p<2; ++p){
      const u32 ap = aPk[mt][p];
      const h2 hl = u2h(__builtin_amdgcn_perm(ap, ap, 0x01000100));  // lo f16 dup
      const h2 hh = u2h(__builtin_amdgcn_perm(ap, ap, 0x03020302));  // hi f16 dup
#pragma unroll
      for (int qp=0; qp<4; ++qp)
#pragma unroll
        for (int X=0; X<4; ++X){
          const h2 bt = u2h(jt[qp][X]);
          s[qp][X] += __builtin_elementwise_max(hl + bt, z);
          s[qp][X] += __builtin_elementwise_max(hh + bt, z);
        }
    }
  // reduce over the 4 q-threads
#pragma unroll
  for (int m=0; m<2; ++m){
    const int msk = 16 << m;
#pragma unroll
    for (int qp=0; qp<4; ++qp)
#pragma unroll
      for (int X=0; X<4; ++X)
        s[qp][X] += u2h((u32)__shfl_xor((int)h2u_(s[qp][X]), msk));
  }
  // write own q-slot: local j = mh*16 + q*4 + 2p + {0,1}
#pragma unroll
  for (int qp=0; qp<4; ++qp) if (qp == q){
#pragma unroll
    for (int X=0; X<4; ++X){
      const int mh = X>>1, p = X&1;
      const int j = (mh<<4) + (qp<<2) + (p<<1);
      hu lo, hi; lo.h = s[qp][X].x; hi.h = s[qp][X].y;
      Q[j][n]   = lo.u;
      Q[j+1][n] = hi.u;
    }
  }
}

// pred(own 32 rows x 8) = hd @ dw2 + db2 -> global out (side branch, tid<256)
__device__ __forceinline__ void dec_out(const u16 (*S)[LDP], const u16* __restrict__ dwt,
    float db2v, float* __restrict__ out, int batch, int half, int t, int tid)
{
  const int r = tid>>3, d = tid&7;          // r local 0..31
  float acc = db2v;
#pragma unroll
  for (int c=0; c<16; ++c){
    f16x8 hv = *(const f16x8*)&S[r][c<<3];
    f16x8 wv = *(const f16x8*)(dwt + (d<<7) + (c<<3));
#pragma unroll
    for (int j=0; j<8; ++j)
      acc += (float)hv[j] * (float)wv[j];
  }
  out[(size_t)(batch*NSTEP + t)*(KK*DD) + ((half<<5)+r)*DD + d] = acc;
}

// h0 = relu(gt0 @ ew1 + eb1), full 64 rows (512 threads: 16 rows each)
__device__ __forceinline__ void mlp_in8(const float* pred, const float* __restrict__ W,
    const float* __restrict__ bias, u16 (*O)[LDP], int tid)
{
  const int h = tid & 127, rg = tid >> 7;    // rg in [0,4)
  float wv[DD];
#pragma unroll
  for (int d=0; d<DD; ++d) wv[d] = W[d*HH + h];
  const float bv = bias[h];
  for (int rr=0; rr<16; ++rr){
    const int r = (rg<<4) + rr;
    float v = bv;
#pragma unroll
    for (int d=0; d<DD; ++d) v += pred[r*DD + d] * wv[d];
    O[r][h] = f2h_bits(fmaxf(v, 0.f));
  }
}

// ---------------- prep: fused fp32 weight products -> f16 frags (+ flag zeroing) ----------------
__global__ void prep_kernel(
    const float* __restrict__ ew1, const float* __restrict__ eb1,
    const float* __restrict__ ew2, const float* __restrict__ eb2,
    const float* __restrict__ sw1, const float* __restrict__ sb1,
    const float* __restrict__ sw2, const float* __restrict__ sb2,
    const float* __restrict__ iw1, const float* __restrict__ ib1,
    const float* __restrict__ iw2, const float* __restrict__ ib2,
    const float* __restrict__ uw1, const float* __restrict__ ub1,
    const float* __restrict__ uw2, const float* __restrict__ ub2,
    const float* __restrict__ dw1, const float* __restrict__ db1,
    const float* __restrict__ dw2, const float* __restrict__ db2,
    u16* __restrict__ ws)
{
  const int idx = blockIdx.x * 256 + threadIdx.x;
  if (idx < 512) ((u32*)(ws + O_FLAG))[idx] = 0;   // zero exchange flags each launch
  if (idx < 49152){
    // EWA / EWB / EWS frags
    const int mat = idx >> 14, r = idx & 16383;
    const int g = r >> 11, kc = (r >> 9) & 3, lane = (r >> 3) & 63, e = r & 7;
    const int k  = (kc<<5) + ((lane>>4)<<3) + e;
    const int nn = (g<<4) + (lane & 15);
    float v = 0.f;
    if (mat == 0){ for (int m=0; m<HH; ++m) v += ew2[k*HH+m] * iw1[m*HH+nn]; }
    else if (mat == 1){ for (int m=0; m<HH; ++m) v += ew2[k*HH+m] * iw1[(HH+m)*HH+nn]; }
    else { for (int m=0; m<HH; ++m) v += ew2[k*HH+m] * sw1[m*HH+nn]; }
    hu hb; hb.h = (f16)v; ws[idx] = hb.u;
  } else if (idx < 81920){
    // SUIU (K=256) frags: kc<4 -> SU, kc>=4 -> IU/64
    const int r = idx - 49152;
    const int g = r >> 12, kc = (r >> 9) & 7, lane = (r >> 3) & 63, e = r & 7;
    const int k  = ((kc&3)<<5) + ((lane>>4)<<3) + e;
    const int nn = (g<<4) + (lane & 15);
    float v = 0.f;
    if (kc < 4){ for (int m=0; m<HH; ++m) v += sw2[k*HH+m] * uw1[m*HH+nn]; }
    else { for (int m=0; m<HH; ++m) v += iw2[k*HH+m] * uw1[(HH+m)*HH+nn]; v *= (1.f/64.f); }
    hu hb; hb.h = (f16)v; ws[idx] = hb.u;
  } else if (idx < 98304){
    // UD frags
    const int r = idx - 81920;
    const int g = r >> 11, kc = (r >> 9) & 3, lane = (r >> 3) & 63, e = r & 7;
    const int k  = (kc<<5) + ((lane>>4)<<3) + e;
    const int nn = (g<<4) + (lane & 15);
    float v = 0.f;
    for (int m=0; m<HH; ++m) v += uw2[k*HH+m] * dw1[m*HH+nn];
    hu hb; hb.h = (f16)v; ws[idx] = hb.u;
  } else if (idx < 114688){
    // DET frags: DE = dw2 @ ew1  (K=8 inner)
    const int r = idx - 98304;
    const int g = r >> 11, kc = (r >> 9) & 3, lane = (r >> 3) & 63, e = r & 7;
    const int k  = (kc<<5) + ((lane>>4)<<3) + e;
    const int nn = (g<<4) + (lane & 15);
    float v = 0.f;
#pragma unroll
    for (int d=0; d<DD; ++d) v += dw2[k*DD+d] * ew1[d*HH+nn];
    hu hb; hb.h = (f16)v; ws[idx] = hb.u;
  } else if (idx < 115712){
    const int r = idx - 114688, d = r >> 7, hcol = r & 127;   // dw2T [8][128]
    hu hb; hb.h = (f16)dw2[hcol*DD + d]; ws[idx] = hb.u;
  } else if (idx < 116480){
    // fused biases (f32)
    const int j = idx - 115712, which = j >> 7, nn = j & 127;
    float v = 0.f;
    switch (which){
      case 0: for (int m=0; m<HH; ++m) v += eb2[m] * iw1[m*HH+nn]; break;                  // bA
      case 1: for (int m=0; m<HH; ++m) v += eb2[m] * iw1[(HH+m)*HH+nn]; v += ib1[nn]; break; // bB
      case 2: for (int m=0; m<HH; ++m) v += eb2[m] * sw1[m*HH+nn]; v += sb1[nn]; break;    // bS
      case 3: for (int m=0; m<HH; ++m) v += sb2[m]*uw1[m*HH+nn] + ib2[m]*uw1[(HH+m)*HH+nn];
              v += ub1[nn]; break;                                                          // bU
      case 4: for (int m=0; m<HH; ++m) v += ub2[m] * dw1[m*HH+nn]; v += db1[nn]; break;    // bUD
      default:
#pragma unroll
        for (int d=0; d<DD; ++d) v += db2[d] * ew1[d*HH+nn];
        v += eb1[nn]; break;                                                                // deb
    }
    ((float*)ws)[BIASF + j] = v;
  }
}

// ---------------- rollout: 2 blocks / batch (256 blocks, all CUs), 512 threads ----------------
// Every GEMM in the step is row-local; the only cross-row coupling is the interaction's
// sum over i, which the fused stage already satisfies by computing full-height a,b in
// registers from the full h state. So each block of a pair keeps full h (64x128) in LDS,
// produces only its 32-row half of Ssum/hu/hd/h_next (halving per-CU VALU+MFMA+LDS), and
// the pair exchanges 8KB h_next halves per step through ws with a parity-double-buffered,
// step-tagged device-scope flag handshake (flags zeroed by prep each launch; blocks b and
// b^128 share an XCD under round-robin dispatch, so the spin resolves in L2).
__global__ __launch_bounds__(512, 2) void rollout_kernel(
    const float* __restrict__ gt, const int* __restrict__ rollout,
    const float* __restrict__ ew1, const float* __restrict__ eb1,
    const float* __restrict__ db2,
    u16* __restrict__ ws, float* __restrict__ out)
{
  extern __shared__ u16 smem[];
  u16 (*P)[LDP] = (u16(*)[LDP])smem;                 // full h: 64 rows
  u16 (*Q)[LDP] = (u16(*)[LDP])(smem + 64*LDP);      // Ssum own half: 32 rows
  u16 (*R)[LDP] = (u16(*)[LDP])(smem + 96*LDP);      // hu own half: 32 rows
  u16 (*S)[LDP] = (u16(*)[LDP])(smem + 128*LDP);     // hs/hd own half: 32 rows
  float* predbuf = (float*)Q;                        // 512 f32, init only

  const int tid = threadIdx.x, blk = blockIdx.x;
  const int batch = blk & 127, half = blk >> 7;
  const int w = tid >> 6, lane = tid & 63;
  const int l15 = lane & 15, q = lane >> 4;
  const int wn = w;                                  // 8 waves -> 8 col groups
  const int n = (wn << 4) + l15;

  int ns = rollout[0];
  if (ns > TT-1) ns = TT-1;
  if (ns > NSTEP) ns = NSTEP;
  if (ns < 0) ns = 0;

  // fused per-thread biases (col n)
  const float* bf32 = (const float*)ws;
  const float bAv  = bf32[BIASF + n];
  const float bBv  = bf32[BIASF + 128 + n];
  const float bSv  = bf32[BIASF + 256 + n];
  const float bUv  = bf32[BIASF + 384 + n];
  const float bUDv = bf32[BIASF + 512 + n];
  const float debv = bf32[BIASF + 640 + n];
  const float db2v = db2[tid & 7];

  // exchange bookkeeping
  u16* xbuf  = ws + O_XBUF;
  u32* flags = (u32*)(ws + O_FLAG);
  const int own  = (batch<<1) + half;
  const int prt  = (batch<<1) + (1-half);

  // init: targets copy (own half range) + h0 = relu(gt[:,0]@ew1 + eb1) (full, both compute)
  for (int i=tid; i<NSTEP*KK*DD/2; i+=512)
    out[PREDSZ + batch*(NSTEP*KK*DD) + half*(NSTEP*KK*DD/2) + i]
      = gt[(size_t)batch*(TT*KK*DD) + KK*DD + half*(NSTEP*KK*DD/2) + i];
  predbuf[tid] = gt[(size_t)batch*(TT*KK*DD) + tid];
  __syncthreads();
  mlp_in8(predbuf, ew1, eb1, P, tid);               // P = h0 (64 rows)
  __syncthreads();

  for (int t=0; t<ns; ++t){
    fusedS1I(P, ws, bAv, bBv, bSv, Q, S, wn, half, l15, q, n, lane);  // Q=Ssum, S=hs (own 32)
    __syncthreads();
    gemm256H(S, Q, ws+O_SUIU, bUv, R, wn, l15, q, n, lane);   // R = hu (own 32)
    __syncthreads();
    gemmH<true>(R, ws+O_UD, bUDv, S, wn, l15, q, n, lane);    // S = hd (own 32)
    __syncthreads();
    gemmH<true>(S, ws+O_DET, debv, P + (half<<5), wn, l15, q, n, lane); // P own rows = h_next
    if (tid < 256) dec_out(S, ws+O_DW2T, db2v, out, batch, half, t, tid);
    __syncthreads();

    if (t < ns-1){
      // export own h_next half -> xbuf[own][t&1]  (parity slot safe: partner consumed
      // this slot at step t-2 before it could have produced its step t-1 data)
      const int par = t & 1;
      u16* ob = xbuf + (((own<<1)|par) << 12);
      {
        const int r = tid >> 4, c = (tid & 15) << 3;         // 32 rows x 128 cols, 8 u16 each
        *(f16x8*)(ob + tid*8) = *(const f16x8*)&P[(half<<5)+r][c];
      }
      __syncthreads();
      if (tid == 0){
        __hip_atomic_store(&flags[(own<<1)|par], (u32)(t+1),
                           __ATOMIC_RELEASE, __HIP_MEMORY_SCOPE_AGENT);
        int guard = 0;
        while (__hip_atomic_load(&flags[(prt<<1)|par],
                 __ATOMIC_ACQUIRE, __HIP_MEMORY_SCOPE_AGENT) != (u32)(t+1)
               && guard < (1<<22)){
          ++guard;
          __builtin_amdgcn_s_sleep(1);
        }
      }
      __syncthreads();
      // import partner half into P
      {
        const u16* pb = xbuf + (((prt<<1)|par) << 12);
        const int r = tid >> 4, c = (tid & 15) << 3;
        *(f16x8*)&P[((1-half)<<5)+r][c] = *(const f16x8*)(pb + tid*8);
      }
      __syncthreads();
    }
  }
}

extern "C" void kernel_launch(void* const* d_in, const int* in_sizes, int n_in,
                              void* d_out, int out_size, void* d_ws, size_t ws_size,
                              hipStream_t stream)
{
  const float* gt  = (const float*)d_in[0];
  const int*   rs  = (const int*)d_in[1];
  const float* ew1 = (const float*)d_in[2];
  const float* eb1 = (const float*)d_in[3];
  const float* ew2 = (const float*)d_in[4];
  const float* eb2 = (const float*)d_in[5];
  const float* sw1 = (const float*)d_in[6];
  const float* sb1 = (const float*)d_in[7];
  const float* sw2 = (const float*)d_in[8];
  const float* sb2 = (const float*)d_in[9];
  const float* iw1 = (const float*)d_in[10];
  const float* ib1 = (const float*)d_in[11];
  const float* iw2 = (const float*)d_in[12];
  const float* ib2 = (const float*)d_in[13];
  const float* uw1 = (const float*)d_in[14];
  const float* ub1 = (const float*)d_in[15];
  const float* uw2 = (const float*)d_in[16];
  const float* ub2 = (const float*)d_in[17];
  const float* dw1 = (const float*)d_in[18];
  const float* db1 = (const float*)d_in[19];
  const float* dw2 = (const float*)d_in[20];
  const float* db2 = (const float*)d_in[21];
  float* out = (float*)d_out;
  u16*   ws  = (u16*)d_ws;

  const int smem_bytes = 160 * LDP * (int)sizeof(u16);  // 43520
  (void)hipFuncSetAttribute((const void*)rollout_kernel,
                            hipFuncAttributeMaxDynamicSharedMemorySize, smem_bytes);

  hipLaunchKernelGGL(prep_kernel, dim3(455), dim3(256), 0, stream,
                     ew1, eb1, ew2, eb2, sw1, sb1, sw2, sb2, iw1, ib1, iw2, ib2,
                     uw1, ub1, uw2, ub2, dw1, db1, dw2, db2, ws);
  hipLaunchKernelGGL(rollout_kernel, dim3(2*BB), dim3(512), smem_bytes, stream,
                     gt, rs, ew1, eb1, db2, ws, out);
}